// Round 1
// baseline (9886.806 us; speedup 1.0000x reference)
//
#include <hip/hip_runtime.h>
#include <hip/hip_bf16.h>

// Problem constants
#define BB   128        // batch
#define SS   64         // source positions
#define HH   1024       // hidden
#define EE   512        // embed
#define VV   32000      // vocab
#define TT   31         // decode steps
#define H4   256        // attention feature dim
#define ZLD  2560       // z row: [e(512) | ctx(1024) | h(1024)]

// ---------------------------------------------------------------------------
// Generic fp32 NT GEMM: C[M,N] = (acc? C : 0) + A[M,K] * B[N,K]^T + bias[N]
// BM=BN=64, BK=16, 256 threads, 4x4 per thread.
// ---------------------------------------------------------------------------
#define BMt 64
#define BNt 64
#define BKt 16

__global__ __launch_bounds__(256) void gemm_nt(
    const float* __restrict__ A, int lda,
    const float* __restrict__ B, int ldb,
    float* __restrict__ C, long long ldc,
    const float* __restrict__ bias,
    int K, int accumulate)
{
    __shared__ __align__(16) float As[BKt][BMt + 4];
    __shared__ __align__(16) float Bs[BKt][BNt + 4];

    const int m0 = blockIdx.x * BMt;
    const int n0 = blockIdx.y * BNt;
    const int tid = threadIdx.x;
    const int tx = tid >> 4;   // m group 0..15
    const int ty = tid & 15;   // n group 0..15
    const int lr = tid >> 2;   // loader row 0..63
    const int lk = (tid & 3) * 4; // loader k 0,4,8,12

    float acc[4][4] = {};

    const float* Ap = A + (long long)(m0 + lr) * lda + lk;
    const float* Bp = B + (long long)(n0 + lr) * ldb + lk;

    for (int k0 = 0; k0 < K; k0 += BKt) {
        const float4 av = *(const float4*)(Ap + k0);
        const float4 bv = *(const float4*)(Bp + k0);
        __syncthreads();
        As[lk + 0][lr] = av.x; As[lk + 1][lr] = av.y;
        As[lk + 2][lr] = av.z; As[lk + 3][lr] = av.w;
        Bs[lk + 0][lr] = bv.x; Bs[lk + 1][lr] = bv.y;
        Bs[lk + 2][lr] = bv.z; Bs[lk + 3][lr] = bv.w;
        __syncthreads();
#pragma unroll
        for (int kk = 0; kk < BKt; ++kk) {
            const float4 a4 = *(const float4*)&As[kk][tx * 4];
            const float4 b4 = *(const float4*)&Bs[kk][ty * 4];
            const float ar[4] = {a4.x, a4.y, a4.z, a4.w};
            const float br[4] = {b4.x, b4.y, b4.z, b4.w};
#pragma unroll
            for (int i = 0; i < 4; ++i)
#pragma unroll
                for (int j = 0; j < 4; ++j)
                    acc[i][j] = fmaf(ar[i], br[j], acc[i][j]);
        }
    }

    float bsv[4] = {0.f, 0.f, 0.f, 0.f};
    if (bias) {
        const float4 b4 = *(const float4*)&bias[n0 + ty * 4];
        bsv[0] = b4.x; bsv[1] = b4.y; bsv[2] = b4.z; bsv[3] = b4.w;
    }
#pragma unroll
    for (int i = 0; i < 4; ++i) {
        float* cp = C + (long long)(m0 + tx * 4 + i) * ldc + n0 + ty * 4;
        float4 r;
        r.x = acc[i][0] + bsv[0];
        r.y = acc[i][1] + bsv[1];
        r.z = acc[i][2] + bsv[2];
        r.w = acc[i][3] + bsv[3];
        if (accumulate) {
            const float4 old = *(const float4*)cp;
            r.x += old.x; r.y += old.y; r.z += old.z; r.w += old.w;
        }
        *(float4*)cp = r;
    }
}

// ---------------------------------------------------------------------------
// init: h <- enc_h (into z cols 1536..2559), c <- enc_c
// ---------------------------------------------------------------------------
__global__ __launch_bounds__(256) void init_state(
    const float* __restrict__ enc_h, const float* __restrict__ enc_c,
    float* __restrict__ z, float* __restrict__ c)
{
    const int idx = blockIdx.x * 256 + threadIdx.x;  // 0..131071
    const int b = idx >> 10, hh = idx & 1023;
    c[idx] = enc_c[idx];
    z[b * ZLD + 1536 + hh] = enc_h[idx];
}

// ---------------------------------------------------------------------------
// embedding gather into z cols 0..511
// ---------------------------------------------------------------------------
__global__ __launch_bounds__(128) void gather_e(
    const int* __restrict__ x_tgt, const float* __restrict__ emb,
    float* __restrict__ z, int t)
{
    const int b = blockIdx.x;
    const int tid = threadIdx.x;       // 0..127, 4 floats each
    const int tok = x_tgt[b * 32 + t];
    const float4 v = *(const float4*)(emb + (long long)tok * EE + tid * 4);
    *(float4*)(z + b * ZLD + tid * 4) = v;
}

// ---------------------------------------------------------------------------
// attention score: per (b,s): v = q[b,:] + P[b,s,:]; softmax over 256 feats;
// tanh; dot with wv; + bv  ->  score[b*64+s]
// one wave per (b,s), 4 pairs per 256-thread block
// ---------------------------------------------------------------------------
__global__ __launch_bounds__(256) void att_score(
    const float* __restrict__ q,     // [B,256] (includes ba)
    const float* __restrict__ P,     // [B*S,256]
    const float* __restrict__ wv,    // [256]
    const float* __restrict__ bv,    // [1]
    float* __restrict__ score)       // [B*S]
{
    const int pair = blockIdx.x * 4 + (threadIdx.x >> 6);
    const int lane = threadIdx.x & 63;
    const int b = pair >> 6;

    float v[4];
#pragma unroll
    for (int j = 0; j < 4; ++j)
        v[j] = q[b * H4 + lane + 64 * j] + P[(long long)pair * H4 + lane + 64 * j];

    float m = fmaxf(fmaxf(v[0], v[1]), fmaxf(v[2], v[3]));
#pragma unroll
    for (int off = 32; off > 0; off >>= 1) m = fmaxf(m, __shfl_xor(m, off));

    float p[4];
    float s = 0.f;
#pragma unroll
    for (int j = 0; j < 4; ++j) { p[j] = __expf(v[j] - m); s += p[j]; }
#pragma unroll
    for (int off = 32; off > 0; off >>= 1) s += __shfl_xor(s, off);
    const float inv = 1.f / s;

    float r = 0.f;
#pragma unroll
    for (int j = 0; j < 4; ++j)
        r += tanhf(p[j] * inv) * wv[lane + 64 * j];
#pragma unroll
    for (int off = 32; off > 0; off >>= 1) r += __shfl_xor(r, off);

    if (lane == 0) score[pair] = r + bv[0];
}

// ---------------------------------------------------------------------------
// ctx[b,h] = sum_s score[b,s] * enc_o[b,s,h]  -> z cols 512..1535
// ---------------------------------------------------------------------------
__global__ __launch_bounds__(256) void ctx_kernel(
    const float* __restrict__ score, const float* __restrict__ enc_o,
    float* __restrict__ z)
{
    const int b = blockIdx.x;
    const int t = threadIdx.x;
    const float* eb = enc_o + (long long)b * SS * HH;
    const float* sb = score + b * SS;
    float acc[4] = {0.f, 0.f, 0.f, 0.f};
    for (int s = 0; s < SS; ++s) {
        const float sc = sb[s];
#pragma unroll
        for (int j = 0; j < 4; ++j)
            acc[j] = fmaf(sc, eb[s * HH + t + 256 * j], acc[j]);
    }
#pragma unroll
    for (int j = 0; j < 4; ++j)
        z[b * ZLD + 512 + t + 256 * j] = acc[j];
}

// ---------------------------------------------------------------------------
// LSTM pointwise: gates [B,4096] -> update c, h (h into z cols 1536..)
// ---------------------------------------------------------------------------
__device__ __forceinline__ float sigm(float x) { return 1.f / (1.f + __expf(-x)); }

__global__ __launch_bounds__(256) void lstm_update(
    const float* __restrict__ gates, float* __restrict__ c,
    float* __restrict__ z)
{
    const int idx = blockIdx.x * 256 + threadIdx.x;  // 0..131071
    const int b = idx >> 10, hh = idx & 1023;
    const float* g = gates + b * 4096;
    const float ig = sigm(g[hh]);
    const float fg = sigm(g[1024 + hh]);
    const float gg = tanhf(g[2048 + hh]);
    const float og = sigm(g[3072 + hh]);
    const float cn = fg * c[idx] + ig * gg;
    c[idx] = cn;
    z[b * ZLD + 1536 + hh] = og * tanhf(cn);
}

// ---------------------------------------------------------------------------
extern "C" void kernel_launch(void* const* d_in, const int* in_sizes, int n_in,
                              void* d_out, int out_size, void* d_ws, size_t ws_size,
                              hipStream_t stream)
{
    const float* enc_o = (const float*)d_in[0];
    const float* enc_c = (const float*)d_in[1];
    const float* enc_h = (const float*)d_in[2];
    const int*   x_tgt = (const int*)  d_in[3];
    const float* emb   = (const float*)d_in[4];
    const float* Wa    = (const float*)d_in[5];
    const float* ba    = (const float*)d_in[6];
    const float* wv    = (const float*)d_in[7];
    const float* bv    = (const float*)d_in[8];
    const float* W_ih  = (const float*)d_in[9];
    const float* W_hh  = (const float*)d_in[10];
    const float* b_ih  = (const float*)d_in[11];
    const float* b_hh  = (const float*)d_in[12];
    const float* Wf    = (const float*)d_in[13];
    const float* bf    = (const float*)d_in[14];
    float* out = (float*)d_out;

    // workspace layout (floats)
    float* w = (float*)d_ws;
    float* P     = w;                 w += (long long)BB * SS * H4;  // 2,097,152
    float* q     = w;                 w += BB * H4;                  //    32,768
    float* score = w;                 w += BB * SS;                  //     8,192
    float* z     = w;                 w += BB * ZLD;                 //   327,680
    float* cbuf  = w;                 w += BB * HH;                  //   131,072
    float* gates = w;                 w += BB * 4 * HH;              //   524,288

    // ---- setup: P = enc_o @ WaH^T   (step-invariant part of attention) ----
    {
        dim3 g(BB * SS / BMt, H4 / BNt);   // 128 x 4
        gemm_nt<<<g, 256, 0, stream>>>(enc_o, HH, Wa + EE, EE + HH,
                                       P, H4, nullptr, HH, 0);
    }
    // ---- init h, c ----
    init_state<<<dim3(BB * HH / 256), 256, 0, stream>>>(enc_h, enc_c, z, cbuf);

    for (int t = 0; t < TT; ++t) {
        // e_t = emb[tok]  -> z[:, 0:512]
        gather_e<<<dim3(BB), 128, 0, stream>>>(x_tgt, emb, z, t);

        // q = e @ WaE^T + ba   [B,256]
        gemm_nt<<<dim3(BB / BMt, H4 / BNt), 256, 0, stream>>>(
            z, ZLD, Wa, EE + HH, q, H4, ba, EE, 0);

        // score[b,s]
        att_score<<<dim3(BB * SS / 4), 256, 0, stream>>>(q, P, wv, bv, score);

        // ctx -> z[:, 512:1536]
        ctx_kernel<<<dim3(BB), 256, 0, stream>>>(score, enc_o, z);

        // gates = [e|ctx] @ W_ih^T + b_ih
        gemm_nt<<<dim3(BB / BMt, 4 * HH / BNt), 256, 0, stream>>>(
            z, ZLD, W_ih, EE + HH, gates, 4 * HH, b_ih, EE + HH, 0);
        // gates += h @ W_hh^T + b_hh
        gemm_nt<<<dim3(BB / BMt, 4 * HH / BNt), 256, 0, stream>>>(
            z + 1536, ZLD, W_hh, HH, gates, 4 * HH, b_hh, HH, 1);

        // LSTM pointwise -> new h (in z), new c
        lstm_update<<<dim3(BB * HH / 256), 256, 0, stream>>>(gates, cbuf, z);

        // logits = h @ Wf^T + bf  -> out[:, t, :]
        gemm_nt<<<dim3(BB / BMt, VV / BNt), 256, 0, stream>>>(
            z + 1536, ZLD, Wf, HH, out + (long long)t * VV,
            (long long)TT * VV, bf, HH, 0);
    }
}